// Round 14
// baseline (1119.299 us; speedup 1.0000x reference)
//
#include <hip/hip_runtime.h>
#include <stdint.h>

typedef short short8 __attribute__((ext_vector_type(8)));
typedef unsigned short u16x4 __attribute__((ext_vector_type(4)));
typedef float floatx16 __attribute__((ext_vector_type(16)));

#define NPTS 16384
#define TILE_M 64
#define THREADS 1024
#define PA 2   // A-fragment (LDS) prefetch depth
#define PB 4   // B-fragment prefetch depth (single stream)

// f32 -> bf16 RNE via hardware cvt; bit-identical to add-round-shift.
__device__ inline unsigned short f2bf(float f) {
  __bf16 h = (__bf16)f;
  return __builtin_bit_cast(unsigned short, h);
}
__device__ inline float bf2f(unsigned short h) {
  union { unsigned u; float f; } v; v.u = ((unsigned)h) << 16;
  return v.f;
}

// De-convoy stagger (round 10: -30 us).
__device__ inline void wave_stagger(int wid) {
  int steps = ((wid >> 2) & 3) * 4 + (wid & 3);
  for (int d = 0; d < steps; ++d)
    asm volatile("s_nop 7\n\ts_nop 7\n\ts_nop 7\n\ts_nop 7\n\ts_nop 7" :::);
}

// Persistent NODE integrator: 1024 threads (16 waves), TILE_M=64, 256 WGs ->
// 4 waves/SIMD. Double-buffered act, same-B k-loop, swapped-operand MFMA
// (D^T: reg -> column, lane -> point).
// NEW: phase 4 deleted. GEMM2's epilogue computes the W4 flow projection
// in-register from its accumulator output (h quantized via bf16 round-trip,
// bit-identical values to the old LDS path), folds the two half-lane
// col-sets with shfl_xor(32), writes 6 partial floats/thread to an
// odd-pitch (conflict-free) partial array; a 192-thread reduce does
// tanh + RK4 update. Removes epi2's 64 KB act write + p4's 64 KB act
// read + w4 re-reads + p4's instruction stream.
__global__
__attribute__((amdgpu_flat_work_group_size(THREADS, THREADS),
               amdgpu_waves_per_eu(4, 4)))
void node_kernel(
    const float* __restrict__ x, float* __restrict__ outp,
    const unsigned short* __restrict__ wbf, const float* __restrict__ sfall,
    const float* __restrict__ w1a, const float* __restrict__ b1a,
    const float* __restrict__ b2a, const float* __restrict__ b3a,
    const float* __restrict__ w4a, const float* __restrict__ b4a,
    const float* __restrict__ w1b, const float* __restrict__ b1b,
    const float* __restrict__ b2b, const float* __restrict__ b3b,
    const float* __restrict__ w4b, const float* __restrict__ b4b)
{
  // each act buffer: 64 x 512 bf16, row pitch 520 u16 (1040 B = 65*16B ->
  // afrag b128 reads land row r on bank-quad r%8 => conflict-free). 65 KB x2.
  __shared__ unsigned short actA[TILE_M][520];
  __shared__ unsigned short actB2[TILE_M][520];
  __shared__ float pcur4[TILE_M][4];  // integrated position (float4 padded)
  __shared__ float pev4[TILE_M][4];   // stage evaluation point
  __shared__ float kac4[TILE_M][4];   // RK4 accumulator
  __shared__ float w4t[512][4];       // W4 col-major (w4t[col][c]), 8 KB
  __shared__ float part[TILE_M][49];  // flow partials, odd pitch 49 dwords
                                      // -> lane->row writes conflict-free

  const int tid = threadIdx.x;
  const int wg = blockIdx.x;
  const int m0 = wg * TILE_M;
  const int batch = wg >> 6;          // 64 WGs per batch (4096/64)
  const int lane = tid & 63;
  const int wid = tid >> 6;           // 0..15: owns cols [wid*32, wid*32+32)

  // ---- init state from x ----
  if (tid < TILE_M * 3) {
    int m = tid / 3, c = tid % 3;
    float v = x[m0 * 3 + tid];
    pcur4[m][c] = v;
    pev4[m][c] = v;
  }
  __syncthreads();

  // act frag (B-operand): lane holds buf[rb*32+(lane&31)][kt*16+(lane>>5)*8..+8]
  // W frag (A-operand): fragment-major wf[((kt*16 + nt)*64 + lane)*8], nt = wid
  const int aBase = (lane & 31) * 1040 + (lane >> 5) * 16;   // bytes
  const int bcol = wid * 64 + lane;                          // short8 index

  // phase-1 column owned by this thread (2 threads per column, split rows)
  const int p1col = tid & 511;
  const int p1r0 = (tid >> 9) * 32;

  // epilogue indices (swapped C/D layout): lane -> point row, reg -> column
  const int ep_m = lane & 31;
  const int ep_nb = wid * 32 + 4 * (lane >> 5);   // + 8*g + i

  const float dt = 0.05f;

  #pragma unroll 1
  for (int f = 0; f < 2; ++f) {
    const float* w1 = f ? w1b : w1a;
    const float* b1v = f ? b1b : b1a;
    const float* b2v = f ? b2b : b2a;
    const float* b3v = f ? b3b : b3a;
    const float* w4 = f ? w4b : w4a;
    const float* b4v = f ? b4b : b4a;
    const short8* w2p = (const short8*)(wbf + (size_t)(f * 2 + 0) * 262144) + bcol;
    const short8* w3p = (const short8*)(wbf + (size_t)(f * 2 + 1) * 262144) + bcol;

    // hoisted per-block-f phase-1 constants
    const float ww0 = w1[p1col * 3 + 0], ww1 = w1[p1col * 3 + 1], ww2 = w1[p1col * 3 + 2];
    const float bb = b1v[p1col];
    const float ss = sfall[f * 2048 + batch * 512 + p1col];
    const float b40 = b4v[0], b41 = b4v[1], b42 = b4v[2];

    // stage W4 col-major into LDS once per f-block
    for (int i = tid; i < 2048; i += THREADS) {
      int col = i >> 2, c = i & 3;
      w4t[col][c] = (c < 3) ? w4[c * 512 + col] : 0.f;
    }
    __syncthreads();

    #pragma unroll 1
    for (int st = 0; st < 4; ++st) {
      #pragma unroll 1
      for (int stage = 0; stage < 4; ++stage) {
        // issue s=0 B prefetch before phase 1: restart the L2 weight stream
        // while the VALU phase runs (no dependency on act)
        short8 bq[PB];
        #pragma unroll
        for (int i = 0; i < PB - 1; ++i) bq[i] = w2p[i * 1024];

        // ---- phase 1: actA = relu(pev@W1.T + b1) * sf ----
        #pragma unroll 4
        for (int mi = 0; mi < 32; ++mi) {
          int m = p1r0 + mi;
          const float4 pv = *(const float4*)&pev4[m][0];
          float v = fmaf(pv.x, ww0, fmaf(pv.y, ww1, fmaf(pv.z, ww2, bb)));
          v = fmaxf(v, 0.f) * ss;
          actA[m][p1col] = f2bf(v);
        }
        __syncthreads();   // (1) actA complete before GEMM1 reads it

        // ======== GEMM1: h1 = relu(actA@W2.T + b2) + actA -> actB2 ========
        {
          const float* bias = b2v;
          const char* kb = (const char*)&actA[0][0];
          wave_stagger(wid);
          floatx16 acc0{}, acc1{};
          short8 aq0[PA], aq1[PA];
          #pragma unroll
          for (int i = 0; i < PA - 1; ++i) {
            aq0[i] = *(const short8*)(kb + aBase + i * 32);
            aq1[i] = *(const short8*)(kb + aBase + 33280 + i * 32);
          }
          #pragma unroll
          for (int kt = 0; kt < 32; ++kt) {
            int la = kt + PA - 1;
            if (la < 32) {
              aq0[la % PA] = *(const short8*)(kb + aBase + la * 32);
              aq1[la % PA] = *(const short8*)(kb + aBase + 33280 + la * 32);
            }
            int lb = kt + PB - 1;
            if (lb < 32) bq[lb % PB] = w2p[lb * 1024];
            __builtin_amdgcn_s_setprio(1);
            acc0 = __builtin_amdgcn_mfma_f32_32x32x16_bf16(bq[kt % PB], aq0[kt % PA], acc0, 0, 0, 0);
            acc1 = __builtin_amdgcn_mfma_f32_32x32x16_bf16(bq[kt % PB], aq1[kt % PA], acc1, 0, 0, 0);
            __builtin_amdgcn_s_setprio(0);
          }
          // restart W3 stream: L2 latency hides under the epilogue below
          #pragma unroll
          for (int i = 0; i < PB - 1; ++i) bq[i] = w3p[i * 1024];

          // epilogue 1: contiguous b64 residual RMW into actB2 (no barrier:
          // writes the buffer no k-loop is reading)
          #pragma unroll
          for (int g = 0; g < 4; ++g) {
            int n0 = ep_nb + 8 * g;
            const float4 bs = *(const float4*)&bias[n0];
            u16x4 r0 = *(const u16x4*)&actA[ep_m][n0];
            u16x4 r1 = *(const u16x4*)&actA[32 + ep_m][n0];
            u16x4 o0, o1;
            #pragma unroll
            for (int i = 0; i < 4; ++i) {
              float v = fmaxf(acc0[g * 4 + i] + ((const float*)&bs)[i], 0.f)
                        + bf2f((unsigned short)r0[i]);
              o0[i] = f2bf(v);
              v = fmaxf(acc1[g * 4 + i] + ((const float*)&bs)[i], 0.f)
                  + bf2f((unsigned short)r1[i]);
              o1[i] = f2bf(v);
            }
            *(u16x4*)&actB2[ep_m][n0] = o0;
            *(u16x4*)&actB2[32 + ep_m][n0] = o1;
          }
        }
        __syncthreads();   // (2) actB2 complete before GEMM2 reads it

        // ======== GEMM2 + fused flow projection (no LDS h write) ========
        {
          const float* bias = b3v;
          const char* kb = (const char*)&actB2[0][0];
          wave_stagger(wid);
          floatx16 acc0{}, acc1{};
          short8 aq0[PA], aq1[PA];
          #pragma unroll
          for (int i = 0; i < PA - 1; ++i) {
            aq0[i] = *(const short8*)(kb + aBase + i * 32);
            aq1[i] = *(const short8*)(kb + aBase + 33280 + i * 32);
          }
          #pragma unroll
          for (int kt = 0; kt < 32; ++kt) {
            int la = kt + PA - 1;
            if (la < 32) {
              aq0[la % PA] = *(const short8*)(kb + aBase + la * 32);
              aq1[la % PA] = *(const short8*)(kb + aBase + 33280 + la * 32);
            }
            int lb = kt + PB - 1;
            if (lb < 32) bq[lb % PB] = w3p[lb * 1024];
            __builtin_amdgcn_s_setprio(1);
            acc0 = __builtin_amdgcn_mfma_f32_32x32x16_bf16(bq[kt % PB], aq0[kt % PA], acc0, 0, 0, 0);
            acc1 = __builtin_amdgcn_mfma_f32_32x32x16_bf16(bq[kt % PB], aq1[kt % PA], acc1, 0, 0, 0);
            __builtin_amdgcn_s_setprio(0);
          }

          // fused epilogue 2: h2 = relu(acc+b3) + h1 (quantized bf16 round-trip,
          // bit-identical values to the old LDS path), dot with W4 columns.
          float s00 = 0.f, s01 = 0.f, s02 = 0.f, s10 = 0.f, s11 = 0.f, s12 = 0.f;
          #pragma unroll
          for (int g = 0; g < 4; ++g) {
            int n0 = ep_nb + 8 * g;
            const float4 bs = *(const float4*)&bias[n0];
            u16x4 r0 = *(const u16x4*)&actB2[ep_m][n0];
            u16x4 r1 = *(const u16x4*)&actB2[32 + ep_m][n0];
            #pragma unroll
            for (int i = 0; i < 4; ++i) {
              const float4 wv = *(const float4*)&w4t[n0 + i][0];  // broadcast
              float v = fmaxf(acc0[g * 4 + i] + ((const float*)&bs)[i], 0.f)
                        + bf2f((unsigned short)r0[i]);
              float h = bf2f(f2bf(v));
              s00 = fmaf(h, wv.x, s00);
              s01 = fmaf(h, wv.y, s01);
              s02 = fmaf(h, wv.z, s02);
              v = fmaxf(acc1[g * 4 + i] + ((const float*)&bs)[i], 0.f)
                  + bf2f((unsigned short)r1[i]);
              h = bf2f(f2bf(v));
              s10 = fmaf(h, wv.x, s10);
              s11 = fmaf(h, wv.y, s11);
              s12 = fmaf(h, wv.z, s12);
            }
          }
          // fold the two half-lane col-sets (lanes l and l+32 share rows)
          s00 += __shfl_xor(s00, 32); s01 += __shfl_xor(s01, 32); s02 += __shfl_xor(s02, 32);
          s10 += __shfl_xor(s10, 32); s11 += __shfl_xor(s11, 32); s12 += __shfl_xor(s12, 32);
          if (lane < 32) {
            part[ep_m][wid * 3 + 0] = s00;
            part[ep_m][wid * 3 + 1] = s01;
            part[ep_m][wid * 3 + 2] = s02;
            part[32 + ep_m][wid * 3 + 0] = s10;
            part[32 + ep_m][wid * 3 + 1] = s11;
            part[32 + ep_m][wid * 3 + 2] = s12;
          }
        }
        __syncthreads();   // (3) partials complete before reduce

        // ---- reduce + tanh + RK4 stage update (192 threads) ----
        if (tid < TILE_M * 3) {
          int m = tid / 3, c = tid % 3;
          float sum = 0.f;
          #pragma unroll
          for (int w = 0; w < 16; ++w) sum += part[m][w * 3 + c];
          float bv = (c == 0) ? b40 : ((c == 1) ? b41 : b42);
          float fl = tanhf(sum + bv);
          float pc = pcur4[m][c];
          if (stage == 0) {
            kac4[m][c] = fl;
            pev4[m][c] = fmaf(0.5f * dt, fl, pc);
          } else if (stage == 1) {
            kac4[m][c] += 2.f * fl;
            pev4[m][c] = fmaf(0.5f * dt, fl, pc);
          } else if (stage == 2) {
            kac4[m][c] += 2.f * fl;
            pev4[m][c] = fmaf(dt, fl, pc);
          } else {
            float np = fmaf(dt / 6.f, kac4[m][c] + fl, pc);
            pcur4[m][c] = np;
            pev4[m][c] = np;
          }
        }
        __syncthreads();   // (4) pev consumers done before next p1
      }
    }
  }

  // ---- write final positions ----
  if (tid < TILE_M * 3) outp[m0 * 3 + tid] = pcur4[tid / 3][tid % 3];
}

// ---- setup: shuffle W (512x512 fp32 row-major, W[n][k]) into fragment-major
// bf16: dst[((kt*16 + nt)*64 + lane)*8 + j] = W[nt*32+(lane&31)][kt*16+(lane>>5)*8+j]
__global__ void setup_shuffle(const float* s0, const float* s1, const float* s2,
                              const float* s3, unsigned short* dst) {
  int idx = blockIdx.x * blockDim.x + threadIdx.x;   // 4 * 32768
  int w = idx >> 15;
  int r = idx & 32767;            // (kt*16+nt)*64 + lane
  int lane = r & 63;
  int tile = r >> 6;
  int nt = tile & 15, kt = tile >> 4;
  const float* W = (w == 0) ? s0 : (w == 1) ? s1 : (w == 2) ? s2 : s3;
  int n = nt * 32 + (lane & 31);
  int k0 = kt * 16 + (lane >> 5) * 8;
  const float* src = W + n * 512 + k0;
  unsigned short* d = dst + ((size_t)w << 18) + (size_t)r * 8;
  #pragma unroll
  for (int j = 0; j < 8; ++j) d[j] = f2bf(src[j]);
}

__global__ void setup_sf(const float* code, const float* cw1, const float* cb1,
                         const float* cw2, const float* cb2, float* sfout) {
  int f = blockIdx.x >> 2, b = blockIdx.x & 3;
  const float* cw = f ? cw2 : cw1;
  const float* cb = f ? cb2 : cb1;
  int j = threadIdx.x;
  const float* c = code + b * 512;
  float s = cb[j];
  for (int k = 0; k < 512; ++k) s = fmaf(c[k], cw[j * 512 + k], s);
  sfout[f * 2048 + b * 512 + j] = tanhf(s);
}

extern "C" void kernel_launch(void* const* d_in, const int* in_sizes, int n_in,
                              void* d_out, int out_size, void* d_ws, size_t ws_size,
                              hipStream_t stream) {
  const float* code = (const float*)d_in[0];
  const float* x    = (const float*)d_in[1];
  char* ws = (char*)d_ws;
  float* sf = (float*)ws;                               // 2*2048 fp32 = 16 KB
  unsigned short* wbf = (unsigned short*)(ws + 16384);  // 4 * 262144 u16 = 2 MB

  setup_shuffle<<<512, 256, 0, stream>>>((const float*)d_in[4], (const float*)d_in[6],
                                         (const float*)d_in[14], (const float*)d_in[16], wbf);
  setup_sf<<<8, 512, 0, stream>>>(code, (const float*)d_in[10], (const float*)d_in[11],
                                  (const float*)d_in[20], (const float*)d_in[21], sf);

  node_kernel<<<NPTS / TILE_M, THREADS, 0, stream>>>(x, (float*)d_out, wbf, sf,
      (const float*)d_in[2], (const float*)d_in[3], (const float*)d_in[5],
      (const float*)d_in[7], (const float*)d_in[8], (const float*)d_in[9],
      (const float*)d_in[12], (const float*)d_in[13], (const float*)d_in[15],
      (const float*)d_in[17], (const float*)d_in[18], (const float*)d_in[19]);
}